// Round 5
// baseline (609.333 us; speedup 1.0000x reference)
//
#include <hip/hip_runtime.h>
#include <hip/hip_cooperative_groups.h>
#include <math.h>

namespace cg = cooperative_groups;

#define H_IMG 768
#define W_IMG 1024
#define NPTS (H_IMG * W_IMG)
#define NITER 10
#define NBLK 256
#define NTHR 256
#define TOTTHR (NBLK * NTHR)
#define PPT (NPTS / TOTTHR)        // 12 points per thread
#define DIST_THR (100.0f / 15.0f)
#define NORMAL_THR 0.34f

struct SharedScratch {
    float  smemF[4][29];
    double smemD[4][29];
    float  pose[12];
};

// ---------------------------------------------------------------- prep: backproject + np.gradient normals
__device__ __forceinline__ void dev_prep(int tid, const float* __restrict__ depth,
                                         const float* __restrict__ K,
                                         float* __restrict__ ref_grid,
                                         float* __restrict__ ref_nrm) {
    float Ki[9];
    {
        double a = K[0], b = K[1], cc = K[2];
        double d = K[3], e = K[4], f = K[5];
        double g = K[6], h = K[7], i = K[8];
        double det = a * (e * i - f * h) - b * (d * i - f * g) + cc * (d * h - e * g);
        double idet = 1.0 / det;
        Ki[0] = (float)((e * i - f * h) * idet);
        Ki[1] = (float)((cc * h - b * i) * idet);
        Ki[2] = (float)((b * f - cc * e) * idet);
        Ki[3] = (float)((f * g - d * i) * idet);
        Ki[4] = (float)((a * i - cc * g) * idet);
        Ki[5] = (float)((cc * d - a * f) * idet);
        Ki[6] = (float)((d * h - e * g) * idet);
        Ki[7] = (float)((b * g - a * h) * idet);
        Ki[8] = (float)((a * e - b * d) * idet);
    }
#pragma unroll
    for (int q = 0; q < PPT; ++q) {
        int p = tid + q * TOTTHR;
        int v = p >> 10, u = p & 1023;
        float uf = (float)u, vf = (float)v;
        float d0 = depth[p];
        float cx = (Ki[0] * uf + Ki[1] * vf + Ki[2]) * d0;
        float cy = (Ki[3] * uf + Ki[4] * vf + Ki[5]) * d0;
        float cz = (Ki[6] * uf + Ki[7] * vf + Ki[8]) * d0;
        ref_grid[3 * p + 0] = cx;
        ref_grid[3 * p + 1] = cy;
        ref_grid[3 * p + 2] = cz;
        int um = u > 0 ? u - 1 : 0, up = u < W_IMG - 1 ? u + 1 : W_IMG - 1;
        int vm = v > 0 ? v - 1 : 0, vp = v < H_IMG - 1 ? v + 1 : H_IMG - 1;
        float su = (u > 0 && u < W_IMG - 1) ? 0.5f : 1.0f;
        float sv = (v > 0 && v < H_IMG - 1) ? 0.5f : 1.0f;
        float dl = depth[v * W_IMG + um], dr = depth[v * W_IMG + up];
        float dt = depth[vm * W_IMG + u], db = depth[vp * W_IMG + u];
        float umf = (float)um, upf = (float)up, vmf = (float)vm, vpf = (float)vp;
        float lx = (Ki[0] * umf + Ki[1] * vf + Ki[2]) * dl;
        float ly = (Ki[3] * umf + Ki[4] * vf + Ki[5]) * dl;
        float lz = (Ki[6] * umf + Ki[7] * vf + Ki[8]) * dl;
        float rx = (Ki[0] * upf + Ki[1] * vf + Ki[2]) * dr;
        float ry = (Ki[3] * upf + Ki[4] * vf + Ki[5]) * dr;
        float rz = (Ki[6] * upf + Ki[7] * vf + Ki[8]) * dr;
        float tx = (Ki[0] * uf + Ki[1] * vmf + Ki[2]) * dt;
        float ty = (Ki[3] * uf + Ki[4] * vmf + Ki[5]) * dt;
        float tz = (Ki[6] * uf + Ki[7] * vmf + Ki[8]) * dt;
        float bx = (Ki[0] * uf + Ki[1] * vpf + Ki[2]) * db;
        float by = (Ki[3] * uf + Ki[4] * vpf + Ki[5]) * db;
        float bz = (Ki[6] * uf + Ki[7] * vpf + Ki[8]) * db;
        float dux = (rx - lx) * su, duy = (ry - ly) * su, duz = (rz - lz) * su;
        float dvx = (bx - tx) * sv, dvy = (by - ty) * sv, dvz = (bz - tz) * sv;
        float nx = duy * dvz - duz * dvy;
        float ny = duz * dvx - dux * dvz;
        float nz = dux * dvy - duy * dvx;
        float il = 1.0f / sqrtf(nx * nx + ny * ny + nz * nz + 1e-12f);
        ref_nrm[3 * p + 0] = nx * il;
        ref_nrm[3 * p + 1] = ny * il;
        ref_nrm[3 * p + 2] = nz * il;
    }
}

// ---------------------------------------------------------------- sweep: residuals + block partial reduce
__device__ __forceinline__ void dev_sweep(int tid,
                                          const float* __restrict__ tp,
                                          const float* __restrict__ tn,
                                          const float* __restrict__ grid,
                                          const float* __restrict__ nrm,
                                          const float* __restrict__ K,
                                          float* __restrict__ partial_row,
                                          SharedScratch* sh) {
    const float R0 = sh->pose[0], R1 = sh->pose[1], R2 = sh->pose[2];
    const float R3 = sh->pose[3], R4 = sh->pose[4], R5 = sh->pose[5];
    const float R6 = sh->pose[6], R7 = sh->pose[7], R8 = sh->pose[8];
    const float t0 = sh->pose[9], t1 = sh->pose[10], t2 = sh->pose[11];
    const float K0 = K[0], K1 = K[1], K2 = K[2];
    const float K3 = K[3], K4 = K[4], K5 = K[5];
    const float K6 = K[6], K7 = K[7], K8 = K[8];

    float acc[29];
#pragma unroll
    for (int k = 0; k < 29; ++k) acc[k] = 0.f;

    for (int q = 0; q < PPT; ++q) {
        int i = tid + q * TOTTHR;
        float p0 = tp[3 * i + 0], p1 = tp[3 * i + 1], p2 = tp[3 * i + 2];
        float n0 = tn[3 * i + 0], n1 = tn[3 * i + 1], n2 = tn[3 * i + 2];
        float d0 = p0 - t0, d1 = p1 - t1, d2 = p2 - t2;
        float pc0 = R0 * d0 + R3 * d1 + R6 * d2;
        float pc1 = R1 * d0 + R4 * d1 + R7 * d2;
        float pc2 = R2 * d0 + R5 * d1 + R8 * d2;
        float nc0 = R0 * n0 + R3 * n1 + R6 * n2;
        float nc1 = R1 * n0 + R4 * n1 + R7 * n2;
        float nc2 = R2 * n0 + R5 * n1 + R8 * n2;
        float uu = K0 * pc0 + K1 * pc1 + K2 * pc2;
        float vv = K3 * pc0 + K4 * pc1 + K5 * pc2;
        float zz = K6 * pc0 + K7 * pc1 + K8 * pc2;
        float zs = (fabsf(zz) > 1e-8f) ? zz : 1e-8f;
        float uf = uu / zs, vf = vv / zs;
        bool valid = (uf > 0.f) && (uf < (float)W_IMG) && (vf > 0.f) && (vf < (float)H_IMG) && (zz > 1e-6f);
        int iu = (int)fminf(fmaxf(uf, 0.f), (float)(W_IMG - 1));
        int iv = (int)fminf(fmaxf(vf, 0.f), (float)(H_IMG - 1));
        int gi = ((iv << 10) + iu) * 3;
        float rg0 = grid[gi + 0], rg1 = grid[gi + 1], rg2 = grid[gi + 2];
        float rn0 = nrm[gi + 0], rn1 = nrm[gi + 1], rn2 = nrm[gi + 2];
        float dd0 = rg0 - pc0, dd1 = rg1 - pc1, dd2 = rg2 - pc2;
        float dist = sqrtf(dd0 * dd0 + dd1 * dd1 + dd2 * dd2 + 1e-12f);
        valid = valid && (dist < DIST_THR) && (rn0 * nc0 + rn1 * nc1 + rn2 * nc2 > NORMAL_THR);
        if (valid) {
            float rw0 = R0 * rg0 + R1 * rg1 + R2 * rg2 + t0;
            float rw1 = R3 * rg0 + R4 * rg1 + R5 * rg2 + t1;
            float rw2 = R6 * rg0 + R7 * rg1 + R8 * rg2 + t2;
            float r = n0 * (rw0 - p0) + n1 * (rw1 - p1) + n2 * (rw2 - p2);
            float J[6];
            J[0] = rw1 * n2 - rw2 * n1;
            J[1] = rw2 * n0 - rw0 * n2;
            J[2] = rw0 * n1 - rw1 * n0;
            J[3] = n0; J[4] = n1; J[5] = n2;
            int cI = 0;
#pragma unroll
            for (int a = 0; a < 6; ++a)
#pragma unroll
                for (int b = a; b < 6; ++b) acc[cI++] += J[a] * J[b];
#pragma unroll
            for (int a = 0; a < 6; ++a) acc[21 + a] += J[a] * r;
            acc[27] += r * r;
            acc[28] += 1.f;
        }
    }

#pragma unroll
    for (int k = 0; k < 29; ++k) {
#pragma unroll
        for (int off = 32; off > 0; off >>= 1) acc[k] += __shfl_down(acc[k], off);
    }
    int lane = threadIdx.x & 63, wv = threadIdx.x >> 6;
    if (lane == 0) {
#pragma unroll
        for (int k = 0; k < 29; ++k) sh->smemF[wv][k] = acc[k];
    }
    __syncthreads();
    if (threadIdx.x < 29) {
        partial_row[threadIdx.x] = sh->smemF[0][threadIdx.x] + sh->smemF[1][threadIdx.x] +
                                   sh->smemF[2][threadIdx.x] + sh->smemF[3][threadIdx.x];
    }
}

// ---------------------------------------------------------------- reduce partials + pivot-free 6x6 solve
// x[] is thread-local; only threadIdx.x==0's copy is authoritative. Writes sh->pose.
__device__ __forceinline__ void dev_reduce_solve(const float* __restrict__ partials,
                                                 double* x, SharedScratch* sh,
                                                 float* __restrict__ out_final) {
    double a2[29];
    const float* row = partials + threadIdx.x * 32;   // NTHR == NBLK: one row per thread
#pragma unroll
    for (int k = 0; k < 29; ++k) a2[k] = (double)row[k];
#pragma unroll
    for (int k = 0; k < 29; ++k) {
#pragma unroll
        for (int off = 32; off > 0; off >>= 1) a2[k] += __shfl_down(a2[k], off);
    }
    int lane = threadIdx.x & 63, wv = threadIdx.x >> 6;
    if (lane == 0) {
#pragma unroll
        for (int k = 0; k < 29; ++k) sh->smemD[wv][k] = a2[k];
    }
    __syncthreads();
    if (threadIdx.x == 0) {
        double T[29];
#pragma unroll
        for (int k = 0; k < 29; ++k)
            T[k] = sh->smemD[0][k] + sh->smemD[1][k] + sh->smemD[2][k] + sh->smemD[3][k];
        double M[6][7];
        int cI = 0;
#pragma unroll
        for (int a = 0; a < 6; ++a)
#pragma unroll
            for (int b = a; b < 6; ++b) { M[a][b] = T[cI]; M[b][a] = T[cI]; ++cI; }
#pragma unroll
        for (int a = 0; a < 6; ++a) M[a][6] = T[21 + a];
        double cost = T[27] / fmax(T[28], 1.0);
#pragma unroll
        for (int d = 0; d < 6; ++d) M[d][d] += 1e-9;
        // pivot-free Gaussian elimination (A is SPD + damping), fully static indices
#pragma unroll
        for (int col = 0; col < 6; ++col) {
            double ip = 1.0 / M[col][col];
#pragma unroll
            for (int r = col + 1; r < 6; ++r) {
                double f = M[r][col] * ip;
#pragma unroll
                for (int k = col; k < 7; ++k) M[r][k] -= f * M[col][k];
            }
        }
        double y[6];
#pragma unroll
        for (int i2 = 5; i2 >= 0; --i2) {
            double s = M[i2][6];
#pragma unroll
            for (int j = i2 + 1; j < 6; ++j) s -= M[i2][j] * y[j];
            y[i2] = s / M[i2][i2];
        }
#pragma unroll
        for (int k = 0; k < 6; ++k) x[k] -= y[k];
        double th2 = x[0] * x[0] + x[1] * x[1] + x[2] * x[2];
        double th = sqrt(th2 + 1e-12);
        double sA = sin(th) / th;
        double sB = (1.0 - cos(th)) / (th2 + 1e-12);
        double R[9];
        R[0] = 1.0 + sB * (-(x[1] * x[1] + x[2] * x[2]));
        R[1] = sA * (-x[2]) + sB * (x[0] * x[1]);
        R[2] = sA * ( x[1]) + sB * (x[0] * x[2]);
        R[3] = sA * ( x[2]) + sB * (x[0] * x[1]);
        R[4] = 1.0 + sB * (-(x[0] * x[0] + x[2] * x[2]));
        R[5] = sA * (-x[0]) + sB * (x[1] * x[2]);
        R[6] = sA * (-x[1]) + sB * (x[0] * x[2]);
        R[7] = sA * ( x[0]) + sB * (x[1] * x[2]);
        R[8] = 1.0 + sB * (-(x[0] * x[0] + x[1] * x[1]));
#pragma unroll
        for (int k = 0; k < 9; ++k) sh->pose[k] = (float)R[k];
        sh->pose[9] = (float)x[3]; sh->pose[10] = (float)x[4]; sh->pose[11] = (float)x[5];
        if (out_final) {
            out_final[0]  = (float)R[0]; out_final[1]  = (float)R[1]; out_final[2]  = (float)R[2]; out_final[3]  = (float)x[3];
            out_final[4]  = (float)R[3]; out_final[5]  = (float)R[4]; out_final[6]  = (float)R[5]; out_final[7]  = (float)x[4];
            out_final[8]  = (float)R[6]; out_final[9]  = (float)R[7]; out_final[10] = (float)R[8]; out_final[11] = (float)x[5];
            out_final[12] = 0.f; out_final[13] = 0.f; out_final[14] = 0.f; out_final[15] = 1.f;
            out_final[16] = (float)cost;
        }
    }
}

// ---------------------------------------------------------------- cooperative single-kernel path
__global__ __launch_bounds__(NTHR) void icp_coop(const float* __restrict__ depth,
                                                 const float* __restrict__ tp,
                                                 const float* __restrict__ tn,
                                                 const float* __restrict__ K,
                                                 float* __restrict__ out,
                                                 float* __restrict__ ref_grid,
                                                 float* __restrict__ ref_nrm,
                                                 float* __restrict__ part0,
                                                 float* __restrict__ part1) {
    __shared__ SharedScratch sh;
    cg::grid_group gg = cg::this_grid();
    const int tid = blockIdx.x * NTHR + threadIdx.x;
    dev_prep(tid, depth, K, ref_grid, ref_nrm);
    double x[6] = {0, 0, 0, 0, 0, 0};
    gg.sync();
    for (int it = 0; it < NITER; ++it) {
        float* pout = (it & 1) ? part1 : part0;
        const float* pprev = (it & 1) ? part0 : part1;
        if (it == 0) {
            if (threadIdx.x == 0) {
                sh.pose[0] = 1.f; sh.pose[1] = 0.f; sh.pose[2] = 0.f;
                sh.pose[3] = 0.f; sh.pose[4] = 1.f; sh.pose[5] = 0.f;
                sh.pose[6] = 0.f; sh.pose[7] = 0.f; sh.pose[8] = 1.f;
                sh.pose[9] = 0.f; sh.pose[10] = 0.f; sh.pose[11] = 0.f;
            }
        } else {
            dev_reduce_solve(pprev, x, &sh, nullptr);
        }
        __syncthreads();
        dev_sweep(tid, tp, tn, ref_grid, ref_nrm, K, pout + blockIdx.x * 32, &sh);
        gg.sync();
    }
    if (blockIdx.x == 0) {
        dev_reduce_solve(part1, x, &sh, out);   // it=9 wrote part1
    }
}

// ---------------------------------------------------------------- fallback multi-dispatch path
__global__ __launch_bounds__(NTHR) void k_prep(const float* __restrict__ depth,
                                               const float* __restrict__ K,
                                               float* __restrict__ ref_grid,
                                               float* __restrict__ ref_nrm) {
    dev_prep(blockIdx.x * NTHR + threadIdx.x, depth, K, ref_grid, ref_nrm);
}

__global__ __launch_bounds__(NTHR) void k_iter(int it, const float* __restrict__ pprev,
                                               float* __restrict__ pout, double* __restrict__ xbuf,
                                               const float* __restrict__ tp, const float* __restrict__ tn,
                                               const float* __restrict__ grid, const float* __restrict__ nrm,
                                               const float* __restrict__ K) {
    __shared__ SharedScratch sh;
    double x[6] = {0, 0, 0, 0, 0, 0};
    if (it == 0) {
        if (threadIdx.x == 0) {
            sh.pose[0] = 1.f; sh.pose[1] = 0.f; sh.pose[2] = 0.f;
            sh.pose[3] = 0.f; sh.pose[4] = 1.f; sh.pose[5] = 0.f;
            sh.pose[6] = 0.f; sh.pose[7] = 0.f; sh.pose[8] = 1.f;
            sh.pose[9] = 0.f; sh.pose[10] = 0.f; sh.pose[11] = 0.f;
        }
    } else {
        if (threadIdx.x == 0) {
#pragma unroll
            for (int k = 0; k < 6; ++k) x[k] = xbuf[k];
        }
        dev_reduce_solve(pprev, x, &sh, nullptr);
    }
    if (threadIdx.x == 0 && blockIdx.x == 0) {
#pragma unroll
        for (int k = 0; k < 6; ++k) xbuf[k] = x[k];
    }
    __syncthreads();
    dev_sweep(blockIdx.x * NTHR + threadIdx.x, tp, tn, grid, nrm, K,
              pout + blockIdx.x * 32, &sh);
}

__global__ __launch_bounds__(NTHR) void k_final(const float* __restrict__ pprev,
                                                double* __restrict__ xbuf,
                                                float* __restrict__ out) {
    __shared__ SharedScratch sh;
    double x[6] = {0, 0, 0, 0, 0, 0};
    if (threadIdx.x == 0) {
#pragma unroll
        for (int k = 0; k < 6; ++k) x[k] = xbuf[k];
    }
    dev_reduce_solve(pprev, x, &sh, out);
}

// ---------------------------------------------------------------- launch
extern "C" void kernel_launch(void* const* d_in, const int* in_sizes, int n_in,
                              void* d_out, int out_size, void* d_ws, size_t ws_size,
                              hipStream_t stream) {
    const float* ref_depth      = (const float*)d_in[0];
    const float* target_pts     = (const float*)d_in[1];
    const float* target_normals = (const float*)d_in[2];
    const float* K              = (const float*)d_in[3];
    float* out = (float*)d_out;
    char* ws = (char*)d_ws;

    const size_t grid_bytes = (size_t)NPTS * 3 * sizeof(float);
    float*  ref_grid = (float*)ws;
    float*  ref_nrm  = (float*)(ws + grid_bytes);
    float*  part0    = (float*)(ws + 2 * grid_bytes);
    float*  part1    = (float*)(ws + 2 * grid_bytes + (size_t)NBLK * 32 * sizeof(float));
    double* xbuf     = (double*)(ws + 2 * grid_bytes + 2 * (size_t)NBLK * 32 * sizeof(float));

    void* args[] = {
        (void*)&ref_depth, (void*)&target_pts, (void*)&target_normals, (void*)&K,
        (void*)&out, (void*)&ref_grid, (void*)&ref_nrm, (void*)&part0, (void*)&part1
    };
    hipError_t err = hipLaunchCooperativeKernel((const void*)icp_coop,
                                                dim3(NBLK), dim3(NTHR), args, 0, stream);
    if (err != hipSuccess) {
        // fallback: proven multi-dispatch pipeline (kernel boundaries = device-wide sync)
        k_prep<<<NBLK, NTHR, 0, stream>>>(ref_depth, K, ref_grid, ref_nrm);
        float* pp[2] = { part0, part1 };
        for (int it = 0; it < NITER; ++it) {
            const float* pprev = (it == 0) ? part1 : pp[(it - 1) & 1];  // unused when it==0
            k_iter<<<NBLK, NTHR, 0, stream>>>(it, pprev, pp[it & 1], xbuf,
                                              target_pts, target_normals, ref_grid, ref_nrm, K);
        }
        k_final<<<1, NTHR, 0, stream>>>(pp[(NITER - 1) & 1], xbuf, out);
    }
}